// Round 5
// baseline (353.021 us; speedup 1.0000x reference)
//
#include <hip/hip_runtime.h>
#include <cstdint>

// MultiBoxLoss (SSD) for MI355X — round 5.
// B=64, P=24564, C=21, M=50. Output: scalar f32.
//
// Pipeline (5 dispatches, no contended atomics):
//   k_match        : per (b,256-prior block): phase1 = per-prior best-truth (fdividef IoU,
//                    stored to LDS tile [256][51]); phase2 = per-m column argmax over the
//                    block -> candidate (iou_bits<<32|p) per (b,m,blk)
//   k_reduce_force : per (b,m): reduce NBX candidates (ascending blk -> first-p ties),
//                    atomicMax(&bt_code[b,p*], FORCED+m)  (max-m == last-m-wins scatter)
//   k_loss         : global_load_lds staged conf -> logsumexp -> ce; pos -> smooth-L1;
//                    ce_neg write; per-block partials (plain stores)
//   k_select       : per-row radix-select k-th largest of ce_neg (k=3*row_pos);
//                    ballot-aggregated digit-3 hist, single-wave shuffle suffix scan
//   k_final        : f64 reduce partials + negsum + row_pos -> scalar

static constexpr int NPB    = 256;         // priors per block
static constexpr int KC     = 21;          // classes
static constexpr int MAXM   = 64;          // >= M (LDS staging)
static constexpr int FORCED = 0x40000000;  // forced-match code offset

typedef unsigned int       u32;
typedef unsigned long long u64;

#define GLOAD_LDS16(gp, lp)                                                        \
  __builtin_amdgcn_global_load_lds((const __attribute__((address_space(1))) u32*)(gp), \
                                   (__attribute__((address_space(3))) u32*)(lp), 16, 0, 0)

// ---------------------------------------------------------------- k_match
__global__ __launch_bounds__(256)
void k_match(const float4* __restrict__ dbox, const float4* __restrict__ gbox,
             int* __restrict__ bt_code, u64* __restrict__ cand, int P, int M, int NBX) {
    int b = blockIdx.y, t = threadIdx.x;
    int p = blockIdx.x * NPB + t;
    __shared__ float4 sg[MAXM];
    __shared__ float  sga[MAXM];
    __shared__ float  siou[NPB][51];   // 51 odd: write addr t*51+m -> all 32 banks, 2-way free
    __shared__ float  sqv[4][64];
    __shared__ int    sqp[4][64];
    if (t < M) {
        float4 g = gbox[b * M + t];
        sg[t]  = g;
        sga[t] = (g.z - g.x) * (g.w - g.y);
    }
    __syncthreads();

    // phase 1: per-prior best truth + store IoU column tile
    if (p < P) {
        float4 d = dbox[p];
        float ad = (d.z - d.x) * (d.w - d.y);
        float bv = -1.f; int bm = 0;
        for (int m = 0; m < M; ++m) {
            float4 g = sg[m];
            float lx = fmaxf(d.x, g.x), ly = fmaxf(d.y, g.y);
            float rx = fminf(d.z, g.z), ry = fminf(d.w, g.w);
            float w = fmaxf(rx - lx, 0.f), h = fmaxf(ry - ly, 0.f);
            float inter = w * h;
            float uni = ad + sga[m] - inter;
            float v = __fdividef(inter, uni);
            siou[t][m] = v;
            if (v > bv) { bv = v; bm = m; }   // strict >: first m wins
        }
        bt_code[(size_t)b * P + p] = (bv >= 0.5f) ? bm : -1;
    } else {
        for (int m = 0; m < M; ++m) siou[t][m] = -2.f;  // below any valid iou
    }
    __syncthreads();

    // phase 2: per-m argmax over the block's 256 priors (4 quarters in parallel)
    int q = t >> 6, m = t & 63;
    if (m < M) {
        float best = -3.f; int bj = 0;
        int rbase = q * 64;
        #pragma unroll 8
        for (int j = 0; j < 64; ++j) {
            float v = siou[rbase + j][m];
            if (v > best) { best = v; bj = j; }  // strict >: first p wins
        }
        sqv[q][m] = best;
        sqp[q][m] = blockIdx.x * NPB + rbase + bj;
    }
    __syncthreads();
    if (t < M) {   // combine quarters ascending (p ascending -> first-p ties)
        float bv2 = -3.f; int bp2 = 0;
        #pragma unroll
        for (int qq = 0; qq < 4; ++qq) {
            float v = sqv[qq][t];
            if (v > bv2) { bv2 = v; bp2 = sqp[qq][t]; }
        }
        if (bv2 < 0.f) bv2 = 0.f;   // defensive (all-invalid quarter can't win)
        cand[((size_t)b * M + t) * NBX + blockIdx.x] =
            ((u64)__float_as_uint(bv2) << 32) | (u32)bp2;
    }
}

// ---------------------------------------------------------------- k_reduce_force
__global__ __launch_bounds__(256)
void k_reduce_force(const u64* __restrict__ cand, int* __restrict__ bt_code,
                    int P, int M, int BM, int NBX) {
    int i = blockIdx.x * 256 + threadIdx.x;
    if (i >= BM) return;
    const u64* cc = cand + (size_t)i * NBX;
    u32 bh = 0, bp = 0;     // all-zero ious -> p=0 (matches ref argmax of zero col)
    for (int j = 0; j < NBX; ++j) {
        u64 kk = cc[j];
        u32 hi = (u32)(kk >> 32);
        if (hi > bh) { bh = hi; bp = (u32)kk; }   // strict >, blk ascending -> first p
    }
    int b = i / M, m = i - b * M;
    atomicMax(&bt_code[(size_t)b * P + (int)bp], FORCED + m);  // max m == last-m-wins
}

// ---------------------------------------------------------------- k_loss
__global__ __launch_bounds__(256)
void k_loss(const float* __restrict__ conf, const float4* __restrict__ locp,
            const float4* __restrict__ dbox, const float4* __restrict__ gbox,
            const int* __restrict__ glab, const int* __restrict__ bt_code,
            float* __restrict__ ce_neg, float2* __restrict__ partials,
            int* __restrict__ poscnt, int P, int M) {
    int b  = blockIdx.y;
    int t  = threadIdx.x;
    int p0 = blockIdx.x * NPB;
    int npr = min(NPB, P - p0);
    __shared__ float slog[NPB * KC];  // 21504 B, linear (global_load_lds: base+lane*16)
    const float* src = conf + ((size_t)b * P + p0) * KC;  // 16B-aligned (84*256 % 16 == 0)
    int nbytes = npr * KC * 4;
    int wave = t >> 6, lane = t & 63;
    int nfull = nbytes >> 10;                      // full 1KB chunks (one per wave-instr)
    for (int j = wave; j < nfull; j += 4) {
        int boff = __builtin_amdgcn_readfirstlane(j << 10);   // UNIFORM LDS offset
        const float* g = src + (boff >> 2) + lane * 4;        // per-lane global addr
        GLOAD_LDS16(g, (char*)slog + boff);
    }
    int rem16 = (nbytes & 1023) >> 4;              // leftover 16B units
    if (wave == 0 && lane < rem16) {
        int boff = __builtin_amdgcn_readfirstlane(nfull << 10);
        const float* g = src + (boff >> 2) + lane * 4;
        GLOAD_LDS16(g, (char*)slog + boff);
    }
    int donew = (nfull << 8) + (rem16 << 2);       // dwords staged
    for (int i = donew + t; i < (nbytes >> 2); i += NPB) slog[i] = src[i];  // safety tail
    __syncthreads();

    float sl1 = 0.f, cep = 0.f, posf = 0.f;
    if (t < npr) {
        int p = p0 + t;
        int code = bt_code[(size_t)b * P + p];
        bool pos = code >= 0;
        int  mi  = (code >= FORCED) ? (code - FORCED) : code;
        const float* L = slog + t * KC;  // stride 21 dwords: odd -> 2-way alias, free
        float v[KC];
        #pragma unroll
        for (int c = 0; c < KC; ++c) v[c] = L[c];
        float mx = v[0];
        #pragma unroll
        for (int c = 1; c < KC; ++c) mx = fmaxf(mx, v[c]);
        float s = 0.f;
        #pragma unroll
        for (int c = 0; c < KC; ++c) s += __expf(v[c] - mx);
        int lab = pos ? glab[b * M + mi] : 0;
        float ce = mx + __logf(s) - L[lab];
        ce_neg[(size_t)b * P + p] = pos ? 0.f : ce;
        if (pos) {
            posf = 1.f;
            cep  = ce;
            float4 g = gbox[b * M + mi];
            float4 d = dbox[p];
            float gw = g.z - g.x, gh = g.w - g.y;
            float dw = d.z - d.x, dh = d.w - d.y;
            float e0 = (0.5f * (g.x + g.z) - 0.5f * (d.x + d.z)) / (0.1f * dw);
            float e1 = (0.5f * (g.y + g.w) - 0.5f * (d.y + d.w)) / (0.1f * dh);
            float e2 = __logf(gw / dw) * 5.0f;  // /VAR1=0.2
            float e3 = __logf(gh / dh) * 5.0f;
            float4 lp = locp[(size_t)b * P + p];
            float d0 = fabsf(lp.x - e0), d1 = fabsf(lp.y - e1);
            float d2 = fabsf(lp.z - e2), d3 = fabsf(lp.w - e3);
            sl1  = (d0 < 1.f ? 0.5f * d0 * d0 : d0 - 0.5f);
            sl1 += (d1 < 1.f ? 0.5f * d1 * d1 : d1 - 0.5f);
            sl1 += (d2 < 1.f ? 0.5f * d2 * d2 : d2 - 0.5f);
            sl1 += (d3 < 1.f ? 0.5f * d3 * d3 : d3 - 0.5f);
        }
    }
    #pragma unroll
    for (int o = 32; o; o >>= 1) {
        sl1  += __shfl_down(sl1, o);
        cep  += __shfl_down(cep, o);
        posf += __shfl_down(posf, o);
    }
    __shared__ float red[3][4];
    int wid = t >> 6;
    if ((t & 63) == 0) { red[0][wid] = sl1; red[1][wid] = cep; red[2][wid] = posf; }
    __syncthreads();
    if (t == 0) {
        float A  = red[0][0] + red[0][1] + red[0][2] + red[0][3];
        float Cc = red[1][0] + red[1][1] + red[1][2] + red[1][3];
        float Pp = red[2][0] + red[2][1] + red[2][2] + red[2][3];
        int blk = blockIdx.y * gridDim.x + blockIdx.x;
        partials[blk] = make_float2(A, Cc);     // plain stores — NO atomics
        poscnt[blk]   = (int)(Pp + 0.5f);
    }
}

// ---------------------------------------------------------------- k_select
__global__ __launch_bounds__(1024)
void k_select(const float* __restrict__ ce_neg, const int* __restrict__ poscnt,
              int* __restrict__ row_pos, float* __restrict__ negsum, int P, int NBX) {
    const int NT = 1024;
    int b = blockIdx.x, t = threadIdx.x, lane = t & 63, wid = t >> 6;
    __shared__ int   hist[4][256];
    __shared__ int   ired[16];
    __shared__ float wsum[16];
    __shared__ u32   s_prefix;
    __shared__ int   s_krem, s_k;

    {   // row_pos[b] = sum of this row's per-block pos counts
        int c = 0;
        for (int i = t; i < NBX; i += NT) c += poscnt[b * NBX + i];
        #pragma unroll
        for (int o = 32; o; o >>= 1) c += __shfl_down(c, o);
        if (lane == 0) ired[wid] = c;
        __syncthreads();
        if (t == 0) {
            int s = 0;
            #pragma unroll
            for (int i2 = 0; i2 < 16; ++i2) s += ired[i2];
            s_k = s; row_pos[b] = s;
            s_prefix = 0u; s_krem = 3 * s;
        }
        __syncthreads();
    }
    int k = 3 * s_k;
    const float4* row4 = (const float4*)(ce_neg + (size_t)b * P);
    int P4 = P >> 2;                 // P % 4 == 0
    u32 thr;
    if (k <= 0) {
        thr = 0xFFFFFFFFu;           // select none (finite non-neg bits < 0xFFFFFFFF)
    } else if (k >= P) {
        thr = 0u;                    // select all; positives contribute 0
    } else {
        for (int d = 3; d >= 0; --d) {   // MSB-first radix over float bits (all >= 0)
            for (int i = t; i < 4 * 256; i += NT) ((int*)hist)[i] = 0;
            __syncthreads();
            u32 pre  = s_prefix;
            int krem = s_krem;
            u32 maskhi = (d == 3) ? 0u : (0xFFFFFFFFu << ((d + 1) * 8));
            int sh = 8 * d;
            int* h = hist[wid & 3];
            for (int qq = t; qq < P4; qq += NT) {
                float4 v = row4[qq];
                u32 wv0 = __float_as_uint(v.x), wv1 = __float_as_uint(v.y);
                u32 wv2 = __float_as_uint(v.z), wv3 = __float_as_uint(v.w);
                #pragma unroll
                for (int j = 0; j < 4; ++j) {
                    u32 wb = (j == 0) ? wv0 : (j == 1) ? wv1 : (j == 2) ? wv2 : wv3;
                    bool valid = (wb & maskhi) == pre;
                    int bin = (int)((wb >> sh) & 255u);
                    if (d == 3) {
                        // wave-aggregate: CE exponents cluster in ~5 bins ->
                        // one atomic per distinct bin per wave instead of 64
                        u64 todo = __ballot(valid);
                        while (todo) {
                            int l  = __builtin_ctzll(todo);
                            int bb = __shfl(bin, l);
                            u64 same = __ballot(valid && (bin == bb));
                            if (lane == l) atomicAdd(&h[bb], (int)__builtin_popcountll(same));
                            todo &= ~same;
                        }
                    } else if (valid) {
                        atomicAdd(&h[bin], 1);
                    }
                }
            }
            __syncthreads();
            if (wid == 0) {   // single-wave suffix scan: 4 bins/lane, no barriers
                int v0 = 4 * lane;
                int c0 = hist[0][v0]     + hist[1][v0]     + hist[2][v0]     + hist[3][v0];
                int c1 = hist[0][v0 + 1] + hist[1][v0 + 1] + hist[2][v0 + 1] + hist[3][v0 + 1];
                int c2 = hist[0][v0 + 2] + hist[1][v0 + 2] + hist[2][v0 + 2] + hist[3][v0 + 2];
                int c3 = hist[0][v0 + 3] + hist[1][v0 + 3] + hist[2][v0 + 3] + hist[3][v0 + 3];
                int sl = c0 + c1 + c2 + c3;
                int T = sl;
                #pragma unroll
                for (int o = 1; o < 64; o <<= 1) {       // inclusive suffix over lanes
                    int x = __shfl_down(T, o);
                    if (lane + o < 64) T += x;
                }
                int Tn = T - sl;                          // S(v0+4)
                int S3 = Tn + c3, S2 = S3 + c2, S1 = S2 + c1, S0 = S1 + c0;  // S(v0+j)
                if (S0 >= krem && S1 < krem) { s_prefix = pre | ((u32)(v0    ) << sh); s_krem = krem - S1; }
                if (S1 >= krem && S2 < krem) { s_prefix = pre | ((u32)(v0 + 1) << sh); s_krem = krem - S2; }
                if (S2 >= krem && S3 < krem) { s_prefix = pre | ((u32)(v0 + 2) << sh); s_krem = krem - S3; }
                if (S3 >= krem && Tn < krem) { s_prefix = pre | ((u32)(v0 + 3) << sh); s_krem = krem - Tn; }
            }
            __syncthreads();
        }
        thr = s_prefix;   // bits of k-th largest value
    }
    float partial = 0.f;
    for (int qq = t; qq < P4; qq += NT) {
        float4 v = row4[qq];
        if (__float_as_uint(v.x) >= thr) partial += v.x;
        if (__float_as_uint(v.y) >= thr) partial += v.y;
        if (__float_as_uint(v.z) >= thr) partial += v.z;
        if (__float_as_uint(v.w) >= thr) partial += v.w;
    }
    #pragma unroll
    for (int o = 32; o; o >>= 1) partial += __shfl_down(partial, o);
    __syncthreads();
    if (lane == 0) wsum[wid] = partial;
    __syncthreads();
    if (t == 0) {
        float s = 0.f;
        #pragma unroll
        for (int i = 0; i < 16; ++i) s += wsum[i];
        negsum[b] = s;                  // plain store — NO atomic
    }
}

// ---------------------------------------------------------------- k_final
__global__ __launch_bounds__(256)
void k_final(const float2* __restrict__ partials, const int* __restrict__ row_pos,
             const float* __restrict__ negsum, int nblk, int B, float* __restrict__ out) {
    int t = threadIdx.x;
    double a = 0.0, c = 0.0;
    for (int i = t; i < nblk; i += 256) {
        float2 p = partials[i];
        a += (double)p.x;
        c += (double)p.y;
    }
    double ns = 0.0;
    int np = 0;
    for (int i = t; i < B; i += 256) { ns += (double)negsum[i]; np += row_pos[i]; }
    #pragma unroll
    for (int o = 32; o; o >>= 1) {
        a  += __shfl_down(a, o);
        c  += __shfl_down(c, o);
        ns += __shfl_down(ns, o);
        np += __shfl_down(np, o);
    }
    __shared__ double red[3][4];
    __shared__ int    redn[4];
    int wid = t >> 6;
    if ((t & 63) == 0) { red[0][wid] = a; red[1][wid] = c; red[2][wid] = ns; redn[wid] = np; }
    __syncthreads();
    if (t == 0) {
        double A = red[0][0] + red[0][1] + red[0][2] + red[0][3];
        double C = red[1][0] + red[1][1] + red[1][2] + red[1][3];
        double N = red[2][0] + red[2][1] + red[2][2] + red[2][3];
        int    P_ = redn[0] + redn[1] + redn[2] + redn[3];
        if (P_ < 1) P_ = 1;
        out[0] = (float)((A + C + N) / (double)P_);
    }
}

extern "C" void kernel_launch(void* const* d_in, const int* in_sizes, int n_in,
                              void* d_out, int out_size, void* d_ws, size_t ws_size,
                              hipStream_t stream) {
    const float* loc_preds     = (const float*)d_in[0];
    const float* conf_preds    = (const float*)d_in[1];
    const float* gt_boxes      = (const float*)d_in[2];
    const int*   gt_labels     = (const int*)d_in[3];
    const float* default_boxes = (const float*)d_in[4];

    int P = in_sizes[4] / 4;                // 24564
    int B = in_sizes[0] / (P * 4);          // 64
    int M = in_sizes[3] / B;                // 50
    int BM  = B * M;
    int NBX = (P + NPB - 1) / NPB;          // 96
    int nblk = NBX * B;                     // 6144

    // workspace carve-out (~15.2 MB)
    char* w = (char*)d_ws;
    float2* partials = (float2*)w;             w += (size_t)nblk * sizeof(float2);
    int*    poscnt   = (int*)w;                w += (size_t)nblk * sizeof(int);
    int*    row_pos  = (int*)w;                w += (size_t)B * sizeof(int);
    float*  negsum   = (float*)w;              w += (size_t)B * sizeof(float);
    w = (char*)(((uintptr_t)w + 7) & ~(uintptr_t)7);
    u64*    cand     = (u64*)w;                w += (size_t)BM * NBX * sizeof(u64);
    int*    bt_code  = (int*)w;                w += (size_t)B * P * 4;
    float*  ce_neg   = (float*)w;              w += (size_t)B * P * 4;

    dim3 g1(NBX, B);
    k_match<<<g1, NPB, 0, stream>>>((const float4*)default_boxes, (const float4*)gt_boxes,
                                    bt_code, cand, P, M, NBX);
    k_reduce_force<<<(BM + 255) / 256, 256, 0, stream>>>(cand, bt_code, P, M, BM, NBX);
    k_loss<<<g1, NPB, 0, stream>>>(conf_preds, (const float4*)loc_preds,
                                   (const float4*)default_boxes, (const float4*)gt_boxes,
                                   gt_labels, bt_code, ce_neg, partials, poscnt, P, M);
    k_select<<<B, 1024, 0, stream>>>(ce_neg, poscnt, row_pos, negsum, P, NBX);
    k_final<<<1, 256, 0, stream>>>(partials, row_pos, negsum, nblk, B, (float*)d_out);
}

// Round 6
// 334.021 us; speedup vs baseline: 1.0569x; 1.0569x over previous
//
#include <hip/hip_runtime.h>
#include <cstdint>

// MultiBoxLoss (SSD) for MI355X — round 6.
// B=64, P=24564, C=21, M=50. Output: scalar f32.
//
// Pipeline (6 dispatches, no contended atomics):
//   k_matchA  : per (b,p): best-truth over M via cross-mult compare -> bt_code (m or -1)
//   k_argmaxB : per (b, 4 truths): argmax_p IoU via block reduction -> bp_idx
//   k_force2  : per (b,m): atomicMax(&bt_code[b,p*], FORCED+m) (max-m == last-m-wins)
//   k_loss    : global_load_lds staged conf -> logsumexp -> ce; pos -> smooth-L1;
//               ce_neg write; per-block partials (plain stores)
//   k_select  : per-row 3-pass radix-select (11/11/10 bits, 2048-bin hist) of k-th
//               largest ce_neg (k=3*row_pos); sum >= threshold
//   k_final   : f64 reduce partials + negsum + row_pos -> scalar

static constexpr int NPB    = 256;         // priors per block
static constexpr int KC     = 21;          // classes
static constexpr int MAXM   = 64;          // >= M
static constexpr int FORCED = 0x40000000;  // forced-match code offset

typedef unsigned int       u32;
typedef unsigned long long u64;

#define GLOAD_LDS16(gp, lp)                                                        \
  __builtin_amdgcn_global_load_lds((const __attribute__((address_space(1))) u32*)(gp), \
                                   (__attribute__((address_space(3))) u32*)(lp), 16, 0, 0)

// ---------------------------------------------------------------- k_matchA
__global__ __launch_bounds__(256)
void k_matchA(const float4* __restrict__ dbox, const float4* __restrict__ gbox,
              int* __restrict__ bt_code, int P, int M) {
    int b = blockIdx.y;
    int t = threadIdx.x;
    int p = blockIdx.x * NPB + t;
    __shared__ float4 sg[MAXM];
    __shared__ float  sga[MAXM];
    if (t < M) {
        float4 g = gbox[b * M + t];
        sg[t]  = g;
        sga[t] = (g.z - g.x) * (g.w - g.y);
    }
    __syncthreads();
    if (p >= P) return;
    float4 d = dbox[p];
    float ad = (d.z - d.x) * (d.w - d.y);
    float bi = 0.f, bu = 1.f;   // best (inter, union); ratio compare via cross-mult
    int bm = 0;
    for (int m = 0; m < M; ++m) {
        float4 g = sg[m];
        float lx = fmaxf(d.x, g.x), ly = fmaxf(d.y, g.y);
        float rx = fminf(d.z, g.z), ry = fminf(d.w, g.w);
        float w = fmaxf(rx - lx, 0.f), h = fmaxf(ry - ly, 0.f);
        float inter = w * h;
        float uni = ad + sga[m] - inter;
        if (inter * bu > bi * uni) { bi = inter; bu = uni; bm = m; }  // strict >: first m wins
    }
    // pos iff iou >= 0.5  <=>  2*inter >= union
    bt_code[(size_t)b * P + p] = (2.f * bi >= bu) ? bm : -1;
}

// ---------------------------------------------------------------- k_argmaxB (4 truths/block)
__global__ __launch_bounds__(256)
void k_argmaxB(const float4* __restrict__ dbox, const float4* __restrict__ gbox,
               int* __restrict__ bp_idx, int P, int M) {
    int b  = blockIdx.y;
    int m0 = blockIdx.x * 4;
    int t  = threadIdx.x;
    int nm = min(4, M - m0);
    float4 g[4]; float ga[4], bi[4], bu[4]; int bp[4];
    #pragma unroll
    for (int j = 0; j < 4; ++j) {
        int mm = m0 + ((j < nm) ? j : (nm - 1));   // dup last for inactive slots
        g[j]  = gbox[b * M + mm];
        ga[j] = (g[j].z - g[j].x) * (g[j].w - g[j].y);
        bi[j] = 0.f; bu[j] = 1.f; bp[j] = 0x7FFFFFFF;
    }
    for (int p = t; p < P; p += NPB) {
        float4 d = dbox[p];
        float ad = (d.z - d.x) * (d.w - d.y);
        #pragma unroll
        for (int j = 0; j < 4; ++j) {
            float lx = fmaxf(d.x, g[j].x), ly = fmaxf(d.y, g[j].y);
            float rx = fminf(d.z, g[j].z), ry = fminf(d.w, g[j].w);
            float w = fmaxf(rx - lx, 0.f), h = fmaxf(ry - ly, 0.f);
            float inter = w * h;
            float uni = ad + ga[j] - inter;
            float l = inter * bu[j], r = bi[j] * uni;
            if (l > r || (l == r && p < bp[j])) { bi[j] = inter; bu[j] = uni; bp[j] = p; }
        }
    }
    #pragma unroll
    for (int o = 32; o; o >>= 1) {   // 64-lane butterfly, lexicographic (-iou, p)
        #pragma unroll
        for (int j = 0; j < 4; ++j) {
            float oi = __shfl_xor(bi[j], o), ou = __shfl_xor(bu[j], o);
            int   op = __shfl_xor(bp[j], o);
            float l = oi * bu[j], r = bi[j] * ou;
            if (l > r || (l == r && op < bp[j])) { bi[j] = oi; bu[j] = ou; bp[j] = op; }
        }
    }
    __shared__ float wi[4][4], wu[4][4];
    __shared__ int   wp[4][4];
    int wid = t >> 6;
    if ((t & 63) == 0) {
        #pragma unroll
        for (int j = 0; j < 4; ++j) { wi[j][wid] = bi[j]; wu[j][wid] = bu[j]; wp[j][wid] = bp[j]; }
    }
    __syncthreads();
    if (t == 0) {
        #pragma unroll
        for (int j = 0; j < 4; ++j) {
            float ci = bi[j], cu = bu[j]; int cp = bp[j];
            #pragma unroll
            for (int w = 1; w < 4; ++w) {
                float l = wi[j][w] * cu, r = ci * wu[j][w];
                if (l > r || (l == r && wp[j][w] < cp)) { ci = wi[j][w]; cu = wu[j][w]; cp = wp[j][w]; }
            }
            if (j < nm) bp_idx[b * M + m0 + j] = cp;
        }
    }
}

// ---------------------------------------------------------------- k_force2
__global__ __launch_bounds__(256)
void k_force2(const int* __restrict__ bp_idx, int* __restrict__ bt_code, int P, int M, int BM) {
    int i = blockIdx.x * blockDim.x + threadIdx.x;
    if (i >= BM) return;
    int b = i / M, m = i - b * M;
    int p = bp_idx[i];
    atomicMax(&bt_code[(size_t)b * P + p], FORCED + m);  // max m == sequential last-m-wins
}

// ---------------------------------------------------------------- k_loss
__global__ __launch_bounds__(256)
void k_loss(const float* __restrict__ conf, const float4* __restrict__ locp,
            const float4* __restrict__ dbox, const float4* __restrict__ gbox,
            const int* __restrict__ glab, const int* __restrict__ bt_code,
            float* __restrict__ ce_neg, float2* __restrict__ partials,
            int* __restrict__ poscnt, int P, int M) {
    int b  = blockIdx.y;
    int t  = threadIdx.x;
    int p0 = blockIdx.x * NPB;
    int npr = min(NPB, P - p0);
    __shared__ float slog[NPB * KC];  // 21504 B, linear (global_load_lds: base+lane*16)
    const float* src = conf + ((size_t)b * P + p0) * KC;  // 16B-aligned (84*256 % 16 == 0)
    int nbytes = npr * KC * 4;
    int wave = t >> 6, lane = t & 63;
    int nfull = nbytes >> 10;                      // full 1KB chunks (one per wave-instr)
    for (int j = wave; j < nfull; j += 4) {
        int boff = __builtin_amdgcn_readfirstlane(j << 10);   // UNIFORM LDS offset
        const float* gp = src + (boff >> 2) + lane * 4;       // per-lane global addr
        GLOAD_LDS16(gp, (char*)slog + boff);
    }
    int rem16 = (nbytes & 1023) >> 4;              // leftover 16B units
    if (wave == 0 && lane < rem16) {
        int boff = __builtin_amdgcn_readfirstlane(nfull << 10);
        const float* gp = src + (boff >> 2) + lane * 4;
        GLOAD_LDS16(gp, (char*)slog + boff);
    }
    int donew = (nfull << 8) + (rem16 << 2);       // dwords staged
    for (int i = donew + t; i < (nbytes >> 2); i += NPB) slog[i] = src[i];  // safety tail
    __syncthreads();

    float sl1 = 0.f, cep = 0.f, posf = 0.f;
    if (t < npr) {
        int p = p0 + t;
        int code = bt_code[(size_t)b * P + p];
        bool pos = code >= 0;
        int  mi  = (code >= FORCED) ? (code - FORCED) : code;
        const float* L = slog + t * KC;  // stride 21 dwords: odd -> 2-way alias, free
        float v[KC];
        #pragma unroll
        for (int c = 0; c < KC; ++c) v[c] = L[c];
        float mx = v[0];
        #pragma unroll
        for (int c = 1; c < KC; ++c) mx = fmaxf(mx, v[c]);
        float s = 0.f;
        #pragma unroll
        for (int c = 0; c < KC; ++c) s += __expf(v[c] - mx);
        int lab = pos ? glab[b * M + mi] : 0;
        float ce = mx + __logf(s) - L[lab];
        ce_neg[(size_t)b * P + p] = pos ? 0.f : ce;
        if (pos) {
            posf = 1.f;
            cep  = ce;
            float4 gg = gbox[b * M + mi];
            float4 d = dbox[p];
            float gw = gg.z - gg.x, gh = gg.w - gg.y;
            float dw = d.z - d.x, dh = d.w - d.y;
            float e0 = (0.5f * (gg.x + gg.z) - 0.5f * (d.x + d.z)) / (0.1f * dw);
            float e1 = (0.5f * (gg.y + gg.w) - 0.5f * (d.y + d.w)) / (0.1f * dh);
            float e2 = __logf(gw / dw) * 5.0f;  // /VAR1=0.2
            float e3 = __logf(gh / dh) * 5.0f;
            float4 lp = locp[(size_t)b * P + p];
            float d0 = fabsf(lp.x - e0), d1 = fabsf(lp.y - e1);
            float d2 = fabsf(lp.z - e2), d3 = fabsf(lp.w - e3);
            sl1  = (d0 < 1.f ? 0.5f * d0 * d0 : d0 - 0.5f);
            sl1 += (d1 < 1.f ? 0.5f * d1 * d1 : d1 - 0.5f);
            sl1 += (d2 < 1.f ? 0.5f * d2 * d2 : d2 - 0.5f);
            sl1 += (d3 < 1.f ? 0.5f * d3 * d3 : d3 - 0.5f);
        }
    }
    #pragma unroll
    for (int o = 32; o; o >>= 1) {
        sl1  += __shfl_down(sl1, o);
        cep  += __shfl_down(cep, o);
        posf += __shfl_down(posf, o);
    }
    __shared__ float red[3][4];
    int wid = t >> 6;
    if ((t & 63) == 0) { red[0][wid] = sl1; red[1][wid] = cep; red[2][wid] = posf; }
    __syncthreads();
    if (t == 0) {
        float A  = red[0][0] + red[0][1] + red[0][2] + red[0][3];
        float Cc = red[1][0] + red[1][1] + red[1][2] + red[1][3];
        float Pp = red[2][0] + red[2][1] + red[2][2] + red[2][3];
        int blk = blockIdx.y * gridDim.x + blockIdx.x;
        partials[blk] = make_float2(A, Cc);     // plain stores — NO atomics
        poscnt[blk]   = (int)(Pp + 0.5f);
    }
}

// ---------------------------------------------------------------- k_select
// 3-pass radix over float bits (all >= 0): 11 / 11 / 10 bits, MSB first.
__global__ __launch_bounds__(1024)
void k_select(const float* __restrict__ ce_neg, const int* __restrict__ poscnt,
              int* __restrict__ row_pos, float* __restrict__ negsum, int P, int NBX) {
    const int NT = 1024, NCOPY = 4;
    int b = blockIdx.x, t = threadIdx.x, lane = t & 63, wid = t >> 6;
    __shared__ int   hist[NCOPY][2048];   // 32 KB
    __shared__ int   scn[2048];           //  8 KB
    __shared__ int   seg[16], seg2[16], ired[16];
    __shared__ float wsum[16];
    __shared__ u32   s_prefix;
    __shared__ int   s_krem, s_k;

    {   // row_pos[b] = sum of this row's per-block pos counts
        int c = 0;
        for (int i = t; i < NBX; i += NT) c += poscnt[b * NBX + i];
        #pragma unroll
        for (int o = 32; o; o >>= 1) c += __shfl_down(c, o);
        if (lane == 0) ired[wid] = c;
        __syncthreads();
        if (t == 0) {
            int s = 0;
            #pragma unroll
            for (int i2 = 0; i2 < 16; ++i2) s += ired[i2];
            s_k = s; row_pos[b] = s;
            s_prefix = 0u; s_krem = 3 * s;
        }
        __syncthreads();
    }
    int k = 3 * s_k;
    const float4* row4 = (const float4*)(ce_neg + (size_t)b * P);
    int P4 = P >> 2;                 // P % 4 == 0
    u32 thr;
    if (k <= 0) {
        thr = 0xFFFFFFFFu;           // select none
    } else if (k >= P) {
        thr = 0u;                    // select all; positives contribute 0
    } else {
        #pragma unroll
        for (int pass = 0; pass < 3; ++pass) {
            const int sh    = (pass == 0) ? 21 : (pass == 1) ? 10 : 0;
            const int nbits = (pass == 2) ? 10 : 11;
            const int nb    = 1 << nbits;
            const u32 maskhi = (pass == 0) ? 0u : (0xFFFFFFFFu << (sh + nbits));
            for (int i = t; i < NCOPY * 2048; i += NT) ((int*)hist)[i] = 0;
            __syncthreads();
            u32 pre  = s_prefix;
            int krem = s_krem;
            int* h = hist[wid & (NCOPY - 1)];
            for (int qq = t; qq < P4; qq += NT) {
                float4 v = row4[qq];
                u32 w0 = __float_as_uint(v.x), w1 = __float_as_uint(v.y);
                u32 w2 = __float_as_uint(v.z), w3 = __float_as_uint(v.w);
                if ((w0 & maskhi) == pre) atomicAdd(&h[(w0 >> sh) & (nb - 1)], 1);
                if ((w1 & maskhi) == pre) atomicAdd(&h[(w1 >> sh) & (nb - 1)], 1);
                if ((w2 & maskhi) == pre) atomicAdd(&h[(w2 >> sh) & (nb - 1)], 1);
                if ((w3 & maskhi) == pre) atomicAdd(&h[(w3 >> sh) & (nb - 1)], 1);
            }
            __syncthreads();
            for (int j = t; j < nb; j += NT) {   // total into scn
                int c = 0;
                #pragma unroll
                for (int w = 0; w < NCOPY; ++w) c += hist[w][j];
                scn[j] = c;
            }
            __syncthreads();
            // hierarchical suffix scan: 16 segments of nb/16 bins, 1 segment per wave
            int sb   = nb >> 4;          // 128 or 64
            int nper = sb >> 6;          // 2 or 1
            int base = wid * sb + lane * nper;
            int c0 = scn[base];
            int c1 = (nper == 2) ? scn[base + 1] : 0;
            int sl = c0 + c1;
            int T = sl;
            #pragma unroll
            for (int o = 1; o < 64; o <<= 1) {   // inclusive suffix over lanes
                int x = __shfl_down(T, o);
                if (lane + o < 64) T += x;
            }
            if (lane == 0) seg[wid] = T;
            __syncthreads();
            if (t < 16) {                         // exclusive suffix over segments
                int sse = 0;
                for (int j2 = t + 1; j2 < 16; ++j2) sse += seg[j2];
                seg2[t] = sse;
            }
            __syncthreads();
            int A1 = seg2[wid] + (T - sl);        // suffix strictly after this lane's bins
            int S1 = A1 + c1;
            int S0 = S1 + c0;
            if (nper == 2) {
                if (S0 >= krem && S1 < krem) { s_prefix = pre | ((u32)base << sh);       s_krem = krem - S1; }
                if (S1 >= krem && A1 < krem) { s_prefix = pre | ((u32)(base + 1) << sh); s_krem = krem - A1; }
            } else {
                if (S0 >= krem && A1 < krem) { s_prefix = pre | ((u32)base << sh);       s_krem = krem - A1; }
            }
            __syncthreads();
        }
        thr = s_prefix;   // bits of k-th largest value
    }
    float partial = 0.f;
    for (int qq = t; qq < P4; qq += NT) {
        float4 v = row4[qq];
        if (__float_as_uint(v.x) >= thr) partial += v.x;
        if (__float_as_uint(v.y) >= thr) partial += v.y;
        if (__float_as_uint(v.z) >= thr) partial += v.z;
        if (__float_as_uint(v.w) >= thr) partial += v.w;
    }
    #pragma unroll
    for (int o = 32; o; o >>= 1) partial += __shfl_down(partial, o);
    __syncthreads();
    if (lane == 0) wsum[wid] = partial;
    __syncthreads();
    if (t == 0) {
        float s = 0.f;
        #pragma unroll
        for (int i = 0; i < 16; ++i) s += wsum[i];
        negsum[b] = s;                  // plain store — NO atomic
    }
}

// ---------------------------------------------------------------- k_final
__global__ __launch_bounds__(256)
void k_final(const float2* __restrict__ partials, const int* __restrict__ row_pos,
             const float* __restrict__ negsum, int nblk, int B, float* __restrict__ out) {
    int t = threadIdx.x;
    double a = 0.0, c = 0.0;
    for (int i = t; i < nblk; i += 256) {
        float2 p = partials[i];
        a += (double)p.x;
        c += (double)p.y;
    }
    double ns = 0.0;
    int np = 0;
    for (int i = t; i < B; i += 256) { ns += (double)negsum[i]; np += row_pos[i]; }
    #pragma unroll
    for (int o = 32; o; o >>= 1) {
        a  += __shfl_down(a, o);
        c  += __shfl_down(c, o);
        ns += __shfl_down(ns, o);
        np += __shfl_down(np, o);
    }
    __shared__ double red[3][4];
    __shared__ int    redn[4];
    int wid = t >> 6;
    if ((t & 63) == 0) { red[0][wid] = a; red[1][wid] = c; red[2][wid] = ns; redn[wid] = np; }
    __syncthreads();
    if (t == 0) {
        double A = red[0][0] + red[0][1] + red[0][2] + red[0][3];
        double C = red[1][0] + red[1][1] + red[1][2] + red[1][3];
        double N = red[2][0] + red[2][1] + red[2][2] + red[2][3];
        int    P_ = redn[0] + redn[1] + redn[2] + redn[3];
        if (P_ < 1) P_ = 1;
        out[0] = (float)((A + C + N) / (double)P_);
    }
}

extern "C" void kernel_launch(void* const* d_in, const int* in_sizes, int n_in,
                              void* d_out, int out_size, void* d_ws, size_t ws_size,
                              hipStream_t stream) {
    const float* loc_preds     = (const float*)d_in[0];
    const float* conf_preds    = (const float*)d_in[1];
    const float* gt_boxes      = (const float*)d_in[2];
    const int*   gt_labels     = (const int*)d_in[3];
    const float* default_boxes = (const float*)d_in[4];

    int P = in_sizes[4] / 4;                // 24564
    int B = in_sizes[0] / (P * 4);          // 64
    int M = in_sizes[3] / B;                // 50
    int BM  = B * M;
    int NBX = (P + NPB - 1) / NPB;          // 96
    int nblk = NBX * B;                     // 6144

    // workspace carve-out (~12.7 MB)
    char* w = (char*)d_ws;
    float2* partials = (float2*)w;             w += (size_t)nblk * sizeof(float2);
    int*    poscnt   = (int*)w;                w += (size_t)nblk * sizeof(int);
    int*    row_pos  = (int*)w;                w += (size_t)B * sizeof(int);
    float*  negsum   = (float*)w;              w += (size_t)B * sizeof(float);
    int*    bp_idx   = (int*)w;                w += (size_t)BM * sizeof(int);
    int*    bt_code  = (int*)w;                w += (size_t)B * P * 4;
    float*  ce_neg   = (float*)w;              w += (size_t)B * P * 4;

    dim3 g1(NBX, B);
    k_matchA<<<g1, NPB, 0, stream>>>((const float4*)default_boxes, (const float4*)gt_boxes,
                                     bt_code, P, M);
    dim3 g2((M + 3) / 4, B);
    k_argmaxB<<<g2, NPB, 0, stream>>>((const float4*)default_boxes, (const float4*)gt_boxes,
                                      bp_idx, P, M);
    k_force2<<<(BM + 255) / 256, 256, 0, stream>>>(bp_idx, bt_code, P, M, BM);
    k_loss<<<g1, NPB, 0, stream>>>(conf_preds, (const float4*)loc_preds,
                                   (const float4*)default_boxes, (const float4*)gt_boxes,
                                   gt_labels, bt_code, ce_neg, partials, poscnt, P, M);
    k_select<<<B, 1024, 0, stream>>>(ce_neg, poscnt, row_pos, negsum, P, NBX);
    k_final<<<1, 256, 0, stream>>>(partials, row_pos, negsum, nblk, B, (float*)d_out);
}